// Round 6
// baseline (132.490 us; speedup 1.0000x reference)
//
#include <hip/hip_runtime.h>

// Chamfer loss, N=4, P1=P2=8192, D=3, K=1.
// prep: per side, col-form float4(-2x,-2y,-2z,|p|^2); padded targets w=1e30.
// main: NO LDS, NO barriers. Thread holds MI=4 rows (raw coords) in VGPRs;
//       columns are read with block-uniform addresses -> scalar loads (SMEM
//       pipe) feeding v_fma's single-SGPR operand slot. 3 fma + 0.5 min3/pair.
//       Per-row min + |row|^2 stored straight to ws partials (no epilogue reduce).
// reduce: min over segments, clamp, scale, block-sum, atomicAdd.
constexpr int N = 4;
constexpr int P = 8192;
constexpr int NSEG = 8;
constexpr int SEGC = P / NSEG;      // 1024 cols per segment
constexpr int MI = 4;               // rows per thread
constexpr int ROWS = 256 * MI;      // 1024 rows per block
constexpr int RG = P / ROWS;        // 8 row groups
constexpr size_t TRANS_F = (size_t)2 * N * P * 4;   // floats in trans arrays

__global__ __launch_bounds__(256) void chamfer_prep_kernel(
    const float* __restrict__ pred, const float* __restrict__ targ,
    const int* __restrict__ lens, float4* __restrict__ trans)
{
    const int i = blockIdx.x * 256 + threadIdx.x;    // 0 .. 2*N*P-1
    const int side = i >> 15;                        // 0: pred, 1: targ
    const int b    = (i >> 13) & (N - 1);
    const int j    = i & (P - 1);
    const float* s = (side ? targ : pred) + ((size_t)b * P + j) * 3;
    const float x = s[0], y = s[1], z = s[2];
    float w = fmaf(x, x, fmaf(y, y, z * z));
    if (side == 1 && j >= lens[b]) w = 1e30f;        // pad col: never wins min
    trans[i] = make_float4(-2.f * x, -2.f * y, -2.f * z, w);
}

__global__ __launch_bounds__(256) void chamfer_min_kernel(
    const float* __restrict__ pred, const float* __restrict__ targ,
    const int* __restrict__ lens, const float4* __restrict__ trans,
    float* __restrict__ partial)
{
    const int x   = blockIdx.x;            // 512 blocks
    const int dir = x >> 8;                // 0: pred rows / targ cols
    const int b   = (x >> 6) & (N - 1);
    const int rg  = (x >> 3) & (RG - 1);
    const int seg = x & (NSEG - 1);
    const int row0 = rg * ROWS;
    const int c0   = seg * SEGC;
    const int L    = lens[b];
    const int tid  = threadIdx.x;

    float* slot = partial + (((size_t)dir * N + b) * NSEG + seg) * P + row0;

    if (dir == 1 && row0 >= L) return;     // padded target rows: never read
    if (dir == 0 && c0 >= L) {             // no valid cols: sentinel for reduce
        #pragma unroll
        for (int k = 0; k < MI; ++k) slot[tid + 256 * k] = 1e30f;
        return;
    }

    // rows: raw coords, direct from inputs (prologue only)
    const float* rbase = (dir == 0 ? pred : targ) + (size_t)b * P * 3;
    // cols: transformed, block-uniform stream -> scalar loads
    const float4* __restrict__ csrc =
        trans + ((size_t)(dir == 0 ? 1 : 0) * N + b) * P + c0;

    float rx[MI], ry[MI], rz[MI], x2[MI], best[MI];
    #pragma unroll
    for (int k = 0; k < MI; ++k) {
        const float* p = rbase + (size_t)(row0 + tid + 256 * k) * 3;
        rx[k] = p[0]; ry[k] = p[1]; rz[k] = p[2];
        x2[k] = fmaf(rx[k], rx[k], fmaf(ry[k], ry[k], rz[k] * rz[k]));
        best[k] = 1e30f;
    }

    // uniform full-segment loop (pads carry w=1e30: no masking, fixed trip count)
    #pragma unroll 4
    for (int j = 0; j < SEGC; j += 2) {
        const float4 q0 = csrc[j];         // uniform addr -> s_load_dwordx4
        const float4 q1 = csrc[j + 1];
        #pragma unroll
        for (int k = 0; k < MI; ++k) {
            float d0 = fmaf(rx[k], q0.x, fmaf(ry[k], q0.y, fmaf(rz[k], q0.z, q0.w)));
            float d1 = fmaf(rx[k], q1.x, fmaf(ry[k], q1.y, fmaf(rz[k], q1.z, q1.w)));
            best[k] = fminf(best[k], fminf(d0, d1));    // -> v_min3_f32
        }
    }

    // each row owned by exactly one thread: direct coalesced store, no LDS
    #pragma unroll
    for (int k = 0; k < MI; ++k) slot[tid + 256 * k] = best[k] + x2[k];
}

__global__ __launch_bounds__(256) void chamfer_reduce_kernel(
    const float* __restrict__ partial, const int* __restrict__ lens,
    float* __restrict__ out)
{
    const int item = blockIdx.x * 256 + threadIdx.x;     // 2*N*P = 65536
    const int dir = item >> 15;
    const int b   = (item >> 13) & (N - 1);
    const int p   = item & (P - 1);
    const int L   = lens[b];

    float c = 0.f;
    if (dir == 0 || p < L) {
        const float* base = partial + (((size_t)dir * N + b) * NSEG) * P + p;
        float v = base[0];
        #pragma unroll
        for (int s = 1; s < NSEG; ++s) v = fminf(v, base[(size_t)s * P]);
        v = fmaxf(v, 0.f);
        c = dir ? v / ((float)L * (float)N) : v * (1.0f / ((float)P * (float)N));
    }
    #pragma unroll
    for (int off = 32; off; off >>= 1) c += __shfl_down(c, off, 64);
    __shared__ float acc[4];
    if ((threadIdx.x & 63) == 0) acc[threadIdx.x >> 6] = c;
    __syncthreads();
    if (threadIdx.x == 0) atomicAdd(out, acc[0] + acc[1] + acc[2] + acc[3]);
}

extern "C" void kernel_launch(void* const* d_in, const int* in_sizes, int n_in,
                              void* d_out, int out_size, void* d_ws, size_t ws_size,
                              hipStream_t stream)
{
    const float* pred = (const float*)d_in[0];
    const float* targ = (const float*)d_in[1];
    const int*   lens = (const int*)d_in[2];
    float* out = (float*)d_out;
    float4* trans   = (float4*)d_ws;                 // 1 MB
    float*  partial = (float*)d_ws + TRANS_F;        // 2 MB

    hipMemsetAsync(out, 0, out_size * sizeof(float), stream);
    chamfer_prep_kernel<<<(2 * N * P) / 256, 256, 0, stream>>>(pred, targ, lens, trans);
    chamfer_min_kernel<<<2 * N * RG * NSEG, 256, 0, stream>>>(pred, targ, lens, trans, partial);
    chamfer_reduce_kernel<<<(2 * N * P) / 256, 256, 0, stream>>>(partial, lens, out);
}

// Round 7
// 111.166 us; speedup vs baseline: 1.1918x; 1.1918x over previous
//
#include <hip/hip_runtime.h>

// Chamfer loss, N=4, P1=P2=8192, D=3, K=1.
// prep: points -> float4(-2x,-2y,-2z,|p|^2); padded target cols w=1e30.
// main: rows packed 2-per-lane in float2 (v_pk_fma_f32 / v_pk_min_f32),
//       8 rows/thread, 2048 rows/block; column segment staged once into LDS,
//       read back with wave-uniform ds_read_b128 (broadcast, conflict-free).
//       d2' = |col|^2 - 2 row.col; per 2 cols per row-pair: 6 pk_fma + 2 pk_min.
//       One barrier per block; per-row min + |row|^2 stored straight to ws.
// reduce: min over segments, clamp, scale, block-sum, atomicAdd.
typedef __attribute__((ext_vector_type(2))) float v2f;

constexpr int N = 4;
constexpr int P = 8192;
constexpr int MIP = 4;                 // row-PAIRS per thread (8 rows)
constexpr int ROWS = 256 * MIP * 2;    // 2048 rows per block
constexpr int RG = P / ROWS;           // 4
constexpr size_t TRANS_F = (size_t)2 * N * P * 4;   // floats in trans arrays

__global__ __launch_bounds__(256) void chamfer_prep_kernel(
    const float* __restrict__ pred, const float* __restrict__ targ,
    const int* __restrict__ lens, float4* __restrict__ trans)
{
    const int i = blockIdx.x * 256 + threadIdx.x;    // 0 .. 2*N*P-1
    const int side = i >> 15;                        // 0: pred, 1: targ
    const int b    = (i >> 13) & (N - 1);
    const int j    = i & (P - 1);
    const float* s = (side ? targ : pred) + ((size_t)b * P + j) * 3;
    const float x = s[0], y = s[1], z = s[2];
    float w = fmaf(x, x, fmaf(y, y, z * z));
    if (side == 1 && j >= lens[b]) w = 1e30f;        // pad col: never wins min
    trans[i] = make_float4(-2.f * x, -2.f * y, -2.f * z, w);
}

__global__ __launch_bounds__(256) void chamfer_min_kernel(
    const int* __restrict__ lens, const float4* __restrict__ trans,
    float* __restrict__ partial, int nseg_shift)
{
    const int nseg = 1 << nseg_shift;
    const int segc = P >> nseg_shift;
    const int seg  = blockIdx.x & (nseg - 1);
    const int rg   = blockIdx.x >> nseg_shift;
    const int b    = blockIdx.y;
    const int dir  = blockIdx.z;           // 0: pred rows / targ cols
    const int row0 = rg * ROWS;
    const int c0   = seg * segc;
    const int L    = lens[b];
    const int tid  = threadIdx.x;

    float* slot = partial + (((size_t)dir * N + b) * nseg + seg) * P + row0;

    if (dir == 1 && row0 >= L) return;     // padded target rows: never read
    if (dir == 0 && c0 >= L) {             // no valid cols: sentinel for reduce
        #pragma unroll
        for (int k = 0; k < 2 * MIP; ++k) slot[tid + 256 * k] = 1e30f;
        return;
    }

    const float4* rsrc = trans + ((size_t)(dir == 0 ? 0 : 1) * N + b) * P + row0;
    const float4* csrc = trans + ((size_t)(dir == 0 ? 1 : 0) * N + b) * P + c0;

    // rows: pair k = rows (tid + 512k, tid + 512k + 256), coords recovered *(-0.5)
    v2f rxx[MIP], ryy[MIP], rzz[MIP], rww[MIP], best[MIP];
    #pragma unroll
    for (int k = 0; k < MIP; ++k) {
        const float4 ta = rsrc[tid + 512 * k];
        const float4 tb = rsrc[tid + 512 * k + 256];
        rxx[k] = (v2f){-0.5f * ta.x, -0.5f * tb.x};
        ryy[k] = (v2f){-0.5f * ta.y, -0.5f * tb.y};
        rzz[k] = (v2f){-0.5f * ta.z, -0.5f * tb.z};
        rww[k] = (v2f){ta.w, tb.w};        // |row|^2 (pad rows masked in reduce)
        best[k] = (v2f){1e30f, 1e30f};
    }

    __shared__ float4 buf[1024];           // whole segment tile (<= 16 KB)
    for (int c = tid; c < segc; c += 256) buf[c] = csrc[c];
    __syncthreads();                       // the only barrier

    #pragma unroll 2
    for (int j = 0; j < segc; j += 2) {
        const float4 q0 = buf[j];          // wave-uniform ds_read_b128: broadcast
        const float4 q1 = buf[j + 1];
        #pragma unroll
        for (int k = 0; k < MIP; ++k) {
            v2f d0 = rxx[k] * q0.x + (ryy[k] * q0.y + (rzz[k] * q0.z + q0.w));
            v2f d1 = rxx[k] * q1.x + (ryy[k] * q1.y + (rzz[k] * q1.z + q1.w));
            best[k] = __builtin_elementwise_min(
                best[k], __builtin_elementwise_min(d0, d1));
        }
    }

    #pragma unroll
    for (int k = 0; k < MIP; ++k) {
        const v2f r = best[k] + rww[k];    // min d2' + |row|^2  (= min d2)
        slot[tid + 512 * k]       = r.x;
        slot[tid + 512 * k + 256] = r.y;
    }
}

__global__ __launch_bounds__(256) void chamfer_reduce_kernel(
    const float* __restrict__ partial, const int* __restrict__ lens,
    float* __restrict__ out, int nseg)
{
    const int item = blockIdx.x * 256 + threadIdx.x;     // 2*N*P = 65536
    const int dir = item >> 15;
    const int b   = (item >> 13) & (N - 1);
    const int p   = item & (P - 1);
    const int L   = lens[b];

    float c = 0.f;
    if (dir == 0 || p < L) {
        const float* base = partial + (((size_t)dir * N + b) * nseg) * P + p;
        float v = base[0];
        for (int s = 1; s < nseg; ++s) v = fminf(v, base[(size_t)s * P]);
        v = fmaxf(v, 0.f);
        c = dir ? v / ((float)L * (float)N) : v * (1.0f / ((float)P * (float)N));
    }
    #pragma unroll
    for (int off = 32; off; off >>= 1) c += __shfl_down(c, off, 64);
    __shared__ float acc[4];
    if ((threadIdx.x & 63) == 0) acc[threadIdx.x >> 6] = c;
    __syncthreads();
    if (threadIdx.x == 0) atomicAdd(out, acc[0] + acc[1] + acc[2] + acc[3]);
}

extern "C" void kernel_launch(void* const* d_in, const int* in_sizes, int n_in,
                              void* d_out, int out_size, void* d_ws, size_t ws_size,
                              hipStream_t stream)
{
    const float* pred = (const float*)d_in[0];
    const float* targ = (const float*)d_in[1];
    const int*   lens = (const int*)d_in[2];
    float* out = (float*)d_out;
    float4* trans   = (float4*)d_ws;                 // 1 MB
    float*  partial = (float*)d_ws + TRANS_F;

    // ws need: 1 MB trans + 2*N*nseg*P*4B partial (nseg=32 -> 8 MB)
    int shift = 5;
    while (shift > 3 &&
           ws_size < TRANS_F * 4 + ((size_t)2 * N * P * 4) << shift) --shift;
    // (guard above: keep at least nseg=8)
    if (ws_size < TRANS_F * 4 + (((size_t)2 * N * P * 4) << 5)) shift = 4;
    if (ws_size < TRANS_F * 4 + (((size_t)2 * N * P * 4) << 4)) shift = 3;
    const int nseg = 1 << shift;

    hipMemsetAsync(out, 0, out_size * sizeof(float), stream);
    chamfer_prep_kernel<<<(2 * N * P) / 256, 256, 0, stream>>>(pred, targ, lens, trans);
    dim3 grid(RG << shift, N, 2);
    chamfer_min_kernel<<<grid, 256, 0, stream>>>(lens, trans, partial, shift);
    chamfer_reduce_kernel<<<(2 * N * P) / 256, 256, 0, stream>>>(partial, lens, out, nseg);
}